// Round 4
// baseline (119.967 us; speedup 1.0000x reference)
//
#include <hip/hip_runtime.h>

typedef short bf16x8 __attribute__((ext_vector_type(8)));
typedef float f32x4  __attribute__((ext_vector_type(4)));

#define L_RES 1280
#define A_ATM 14
#define K_NB  30
#define FEAT  656
#define KPAD  672          // 21 * 32
#define NKB   21           // K-blocks of 32
#define NCH   128
#define AF_STRIDE 680      // bf16 elems per LDS A-row (2-way bank aliasing = free)
#define EP_STRIDE 136      // fp32 Epre row stride; quads hit disjoint bank octets
#define E_OUT_OFF (L_RES * K_NB * NCH)
#define NEDGE (L_RES * K_NB)   // 38400

// fp32 -> bf16 round-to-nearest-even
__device__ __forceinline__ ushort f2bf(float x) {
    union { float f; unsigned u; } v; v.f = x;
    unsigned r = (v.u + 0x7fffu + ((v.u >> 16) & 1u)) >> 16;
    return (ushort)r;
}

// Blocks 0..41: W_edge [656][128] fp32 -> Wpack in MFMA-fragment order:
//   Wpack[(((n>>4)*NKB + kb)*64 + (quad*16 + (n&15)))*8 + j] = bf16(W[(kb*32+quad*8+j)*128 + n])
// so a GEMM wave's B load for (ntile,kb) is one contiguous 1KB (lane*16B).
// Blocks 42..191: E_idx passthrough as float into d_out tail.
__global__ __launch_bounds__(256) void prep_kernel(const float* __restrict__ W,
                                                   const int* __restrict__ Eidx,
                                                   ushort* __restrict__ Wpack,
                                                   float* __restrict__ out) {
    const int blk = blockIdx.x;
    const int t = threadIdx.x;
    if (blk < 42) {
        int u = blk * 256 + t;               // 10752 threads, one ushort8 each
        if (u >= 84 * 128) return;
        int kbq = u >> 7;                     // 0..83
        int n   = u & 127;
        int kb   = kbq >> 2;
        int quad = kbq & 3;
        ushort val[8];
#pragma unroll
        for (int j = 0; j < 8; j++) {
            int k = kb * 32 + quad * 8 + j;
            val[j] = (k < FEAT) ? f2bf(W[k * NCH + n]) : (ushort)0;
        }
        int lane = quad * 16 + (n & 15);
        ushort* dst = Wpack + (size_t)((((n >> 4) * NKB + kb) * 64 + lane) * 8);
        *(ulonglong2*)dst = *(const ulonglong2*)val;
    } else {
        int gid = (blk - 42) * 256 + t;
        if (gid < NEDGE) out[E_OUT_OFF + gid] = (float)Eidx[gid];
    }
}

__global__ __launch_bounds__(512) void sidechain_feat_kernel(
    const float* __restrict__ X,
    const int*   __restrict__ ridx,
    const int*   __restrict__ clab,
    const int*   __restrict__ Eidx,
    const float* __restrict__ Wpos,
    const float* __restrict__ bpos,
    const ushort* __restrict__ Wpack,
    const float* __restrict__ gamma,
    const float* __restrict__ beta,
    float* __restrict__ out)
{
    // 64-row A matrix: rows 0..29 = residue i0 edges, 32..61 = residue i0+1
    // (rows 30,31,62,63 zero-padded). Reused as fp32 Epre after the GEMM.
    __shared__ __align__(16) ushort Af[64][AF_STRIDE];   // 87,040 B
    __shared__ float bbs[8][3];                          // bb atoms, 2 residues
    __shared__ float scj[2 * K_NB][10][3];
    __shared__ int   nbr[2 * K_NB];

    const int i0 = blockIdx.x * 2;
    const int t = threadIdx.x;
    const int w = t >> 6;              // wave 0..7
    const int lane = t & 63;

    if (t < 24) {
        const int perm[4] = {1, 0, 2, 3};
        int res = t / 12, r = t - res * 12;
        int a = r / 3, c = r - a * 3;
        bbs[res * 4 + a][c] = X[((i0 + res) * A_ATM + perm[a]) * 3 + c];
    }
    if (t < 2 * K_NB) nbr[t] = Eidx[i0 * K_NB + t];
    __syncthreads();

    for (int idx = t; idx < 2 * K_NB * 30; idx += 512) {   // 60 edges x 10 atoms x 3
        int e = idx / 30;
        int r = idx - e * 30;
        int a = r / 3, c = r - a * 3;
        scj[e][a][c] = X[(nbr[e] * A_ATM + 4 + a) * 3 + c];
    }

    // ---- positional features (cols 0..15): 60 edges x 16 ----
    for (int idx = t; idx < 2 * K_NB * 16; idx += 512) {
        int e = idx >> 4, c = idx & 15;
        int res = i0 + (e >= K_NB);
        int row = e + (e >= K_NB ? 2 : 0);
        int j = nbr[e];
        int d;
        if (clab[res] == clab[j]) {
            int off = ridx[res] - ridx[j] + 32;
            d = off < 0 ? 0 : (off > 64 ? 64 : off);
        } else {
            d = 65;
        }
        Af[row][c] = f2bf(Wpos[d * 16 + c] + bpos[c]);
    }
    // ---- zero pad rows 30,31,62,63; zero k-pad cols 656..679 ----
    for (int idx = t; idx < 4 * AF_STRIDE; idx += 512) {
        int pr = idx / AF_STRIDE;             // 0..3
        int row = (pr & 1) + (pr >> 1) * 32 + 30;
        Af[row][idx % AF_STRIDE] = 0;
    }
    for (int idx = t; idx < 60 * 24; idx += 512) {
        int e = idx / 24;
        int row = e + (e >= K_NB ? 2 : 0);
        Af[row][FEAT + idx % 24] = 0;
    }
    __syncthreads();

    // ---- RBF features: 60 edges x 40 pairs x 16 rbf ----
    for (int idx = t; idx < 2 * K_NB * 40; idx += 512) {
        int e  = idx / 40;
        int p  = idx - e * 40;
        int ab = p / 10, as = p - ab * 10;
        int hi = (e >= K_NB);
        int row = e + hi * 2;
        float dx = bbs[hi * 4 + ab][0] - scj[e][as][0];
        float dy = bbs[hi * 4 + ab][1] - scj[e][as][1];
        float dz = bbs[hi * 4 + ab][2] - scj[e][as][2];
        float dist = sqrtf(dx * dx + dy * dy + dz * dz + 1e-6f);
        bool self = (nbr[e] == i0 + hi);   // AUTOREGRESSIVE self-edge mask
        unsigned* dst = (unsigned*)&Af[row][16 + p * 16];
#pragma unroll
        for (int q = 0; q < 8; q++) {
            float m0 = 2.0f + (float)(2 * q)     * (20.0f / 15.0f);
            float m1 = 2.0f + (float)(2 * q + 1) * (20.0f / 15.0f);
            float a0 = (dist - m0) * 0.8f;
            float a1 = (dist - m1) * 0.8f;
            float r0 = self ? 0.0f : __expf(-a0 * a0);
            float r1 = self ? 0.0f : __expf(-a1 * a1);
            dst[q] = (unsigned)f2bf(r0) | ((unsigned)f2bf(r1) << 16);
        }
    }
    __syncthreads();

    // ---- MFMA GEMM: C[64 x 128] = Af[64 x 672] @ W^T ----
    // wave w owns n-tile w (cols w*16..w*16+15), all 4 m-tiles.
    const int frow = lane & 15;
    const int quad = lane >> 4;
    const ushort* Ap[4];
#pragma unroll
    for (int m = 0; m < 4; m++) Ap[m] = &Af[m * 16 + frow][quad * 8];
    const ushort* Bp = Wpack + (size_t)((w * NKB) * 64 + lane) * 8;

    f32x4 acc[4];
#pragma unroll
    for (int m = 0; m < 4; m++) acc[m] = (f32x4){0.f, 0.f, 0.f, 0.f};

    bf16x8 a[4], b;
#pragma unroll
    for (int m = 0; m < 4; m++) a[m] = *(const bf16x8*)(Ap[m]);
    b = *(const bf16x8*)(Bp);

#pragma unroll
    for (int kb = 0; kb < NKB; kb++) {
        bf16x8 ca[4] = {a[0], a[1], a[2], a[3]};
        bf16x8 cb = b;
        if (kb + 1 < NKB) {            // depth-1 prefetch
#pragma unroll
            for (int m = 0; m < 4; m++) a[m] = *(const bf16x8*)(Ap[m] + (kb + 1) * 32);
            b = *(const bf16x8*)(Bp + (size_t)(kb + 1) * 512);
        }
#pragma unroll
        for (int m = 0; m < 4; m++)
            acc[m] = __builtin_amdgcn_mfma_f32_16x16x32_bf16(ca[m], cb, acc[m], 0, 0, 0);
    }

    __syncthreads();                   // all waves done reading Af
    float (*Epre)[EP_STRIDE] = (float (*)[EP_STRIDE])&Af[0][0];  // 64 x 136 fp32 = 34,816 B

    // C/D layout (m89/m91): col = lane&15, row = quad*4 + reg
#pragma unroll
    for (int m = 0; m < 4; m++)
#pragma unroll
        for (int r = 0; r < 4; r++)
            Epre[m * 16 + quad * 4 + r][w * 16 + frow] = acc[m][r];
    __syncthreads();

    // ---- LayerNorm per edge over 128 channels + store ----
    for (int e = w; e < 2 * K_NB; e += 8) {
        int row = e + (e >= K_NB ? 2 : 0);
        float v0 = Epre[row][lane];
        float v1 = Epre[row][lane + 64];
        float s = v0 + v1;
        float q = v0 * v0 + v1 * v1;
#pragma unroll
        for (int off = 32; off > 0; off >>= 1) {
            s += __shfl_xor(s, off);
            q += __shfl_xor(q, off);
        }
        float mean = s * (1.0f / 128.0f);
        float var  = q * (1.0f / 128.0f) - mean * mean;
        float rstd = rsqrtf(var + 1e-5f);
        int eo = (e >= K_NB) ? (K_NB + e - K_NB) : e;   // = e
        float* o = out + (size_t)((i0 + (e >= K_NB)) * K_NB + (e % K_NB)) * NCH;
        (void)eo;
        o[lane]      = (v0 - mean) * rstd * gamma[lane]      + beta[lane];
        o[lane + 64] = (v1 - mean) * rstd * gamma[lane + 64] + beta[lane + 64];
    }
}

extern "C" void kernel_launch(void* const* d_in, const int* in_sizes, int n_in,
                              void* d_out, int out_size, void* d_ws, size_t ws_size,
                              hipStream_t stream) {
    const float* X     = (const float*)d_in[0];
    const int*   ridx  = (const int*)  d_in[1];
    const int*   clab  = (const int*)  d_in[2];
    const int*   Eidx  = (const int*)  d_in[3];
    // d_in[4] = atom_mask (unused by reference forward)
    const float* Wpos  = (const float*)d_in[5];
    const float* bpos  = (const float*)d_in[6];
    const float* Wedge = (const float*)d_in[7];
    const float* gamma = (const float*)d_in[8];
    const float* beta  = (const float*)d_in[9];
    float* out = (float*)d_out;

    ushort* Wpack = (ushort*)d_ws;   // 128*672*2 = 172,032 B

    prep_kernel<<<42 + (NEDGE + 255) / 256, 256, 0, stream>>>(Wedge, Eidx, Wpack, out);
    sidechain_feat_kernel<<<L_RES / 2, 512, 0, stream>>>(
        X, ridx, clab, Eidx, Wpos, bpos, Wpack, gamma, beta, out);
}